// Round 4
// baseline (364.360 us; speedup 1.0000x reference)
//
#include <hip/hip_runtime.h>

typedef unsigned short u16;
typedef __bf16 bf16x8 __attribute__((ext_vector_type(8)));
typedef float f32x4 __attribute__((ext_vector_type(4)));

// cheap float->bf16: round via +0x8000 then truncate (<=1ulp vs RNE)
__device__ __forceinline__ u16 f2bf_r(float f) {
    union { float f; unsigned u; } v; v.f = f;
    return (u16)((v.u + 0x8000u) >> 16);
}
__device__ __forceinline__ float rcpf(float x) { return __builtin_amdgcn_rcpf(x); }

__device__ __forceinline__ void gload_lds16(const u16* g, u16* l) {
    __builtin_amdgcn_global_load_lds(
        (const __attribute__((address_space(1))) void*)g,
        (__attribute__((address_space(3))) void*)l,
        16, 0, 0);
}

// ---------------------------------------------------------------------------
// Fragment-order LDS layout: elem (row,k) of a [rows][32] bf16 tile lives at
//   (row>>4)*512 + (k>>3)*128 + (row&15)*8 + (k&7)
// MFMA fragment read = 16 consecutive 16B chunks across lanes -> conflict-free.
// Staged with linear LDS dest (global_load_lds) + permuted GLOBAL source:
//   thread t (within a 64-row group) loads row (t>>6)*16+(t&15), kcol ((t>>4)&3)*8
// ---------------------------------------------------------------------------

#define BM 128
#define BN 128
#define BK 32

template<int K, int RELU>
__global__ __launch_bounds__(256) void gemm_bt(
    const u16* __restrict__ A, const u16* __restrict__ BT,
    const float* __restrict__ bias, u16* __restrict__ C,
    int M, int N)
{
    __shared__ u16 As[BM * BK];
    __shared__ u16 Bs[BN * BK];
    const int t = threadIdx.x;
    const int lane = t & 63;
    const int wave = t >> 6;
    const int wr = (wave >> 1) * 64;
    const int wc = (wave & 1) * 64;
    const long brow = (long)blockIdx.y * BM;
    const long bcol = (long)blockIdx.x * BN;

    // permuted staging source (fragment-order layout)
    const int sr = ((t >> 6) << 4) | (t & 15);   // row within 64-row group
    const int sc = ((t >> 4) & 3) * 8;           // k-col (8-elem granule)
    const u16* gA0 = A + (brow + sr) * (long)K + sc;
    const u16* gA1 = gA0 + 64L * K;
    const u16* gB0 = BT + (bcol + sr) * (long)K + sc;
    const u16* gB1 = gB0 + 64L * K;

    f32x4 acc[4][4] = {};
    const int fr  = lane & 15;
    const int fbase = (lane >> 4) * 128 + fr * 8;   // within-chunk frag offset

#pragma unroll
    for (int k0 = 0; k0 < K; k0 += BK) {
        gload_lds16(gA0 + k0, &As[t * 8]);
        gload_lds16(gA1 + k0, &As[2048 + t * 8]);
        gload_lds16(gB0 + k0, &Bs[t * 8]);
        gload_lds16(gB1 + k0, &Bs[2048 + t * 8]);
        __syncthreads();

        bf16x8 af[4], bfr[4];
#pragma unroll
        for (int m = 0; m < 4; ++m)
            af[m] = *(const bf16x8*)&As[((wr >> 4) + m) * 512 + fbase];
#pragma unroll
        for (int n = 0; n < 4; ++n)
            bfr[n] = *(const bf16x8*)&Bs[((wc >> 4) + n) * 512 + fbase];
#pragma unroll
        for (int m = 0; m < 4; ++m)
#pragma unroll
            for (int n = 0; n < 4; ++n)
                acc[m][n] = __builtin_amdgcn_mfma_f32_16x16x32_bf16(
                    af[m], bfr[n], acc[m][n], 0, 0, 0);
        __syncthreads();
    }

#pragma unroll
    for (int n = 0; n < 4; ++n) {
        const long col = bcol + wc + n * 16 + fr;
        const float bv = bias[col];
#pragma unroll
        for (int m = 0; m < 4; ++m) {
            const long row = brow + wr + m * 16 + (lane >> 4) * 4;
#pragma unroll
            for (int j = 0; j < 4; ++j) {
                float v = acc[m][n][j] + bv;
                if (RELU) v = fmaxf(v, 0.f);
                C[(row + j) * (long)N + col] = f2bf_r(v);
            }
        }
    }
}

// ---- fused GEMM3 (64x192 tile) + RQS spline ----
#define FBM 64
#define FBN 192
#define FBK 32
#define CLS 200   // padded LDS row stride (u16) for the C tile

template<int K>
__global__ __launch_bounds__(256) void gemm3_rqs(
    const u16* __restrict__ A,       // h2: B x K bf16
    const u16* __restrict__ BT,      // W2T padded: 1536 x K bf16
    const float* __restrict__ bias,  // b2p: 1536
    const float* __restrict__ x,     // B x 64 fp32
    float* __restrict__ z,           // B x 64 fp32
    float* __restrict__ ldp)         // B x 64 fp32 partial logdet
{
    __shared__ u16 smem[FBM * CLS];          // 25600 B; staging aliases the front
    u16* As = smem;                          // 2048 u16
    u16* Bs = smem + FBM * FBK;              // 6144 u16

    const int t = threadIdx.x;
    const int lane = t & 63;
    const int wave = t >> 6;
    const int wc = wave * 48;                // 4 waves x 48 cols
    const long brow = (long)blockIdx.y * FBM;
    const int bcol = blockIdx.x * FBN;

    const int sr = ((t >> 6) << 4) | (t & 15);
    const int sc = ((t >> 4) & 3) * 8;
    const u16* gA0 = A + (brow + sr) * (long)K + sc;
    const u16* gB0 = BT + (long)(bcol + sr) * K + sc;

    f32x4 acc[4][3] = {};
    const int fr  = lane & 15;
    const int fbase = (lane >> 4) * 128 + fr * 8;

#pragma unroll
    for (int k0 = 0; k0 < K; k0 += FBK) {
        gload_lds16(gA0 + k0,            &As[t * 8]);
        gload_lds16(gB0 + k0,            &Bs[t * 8]);
        gload_lds16(gB0 + 64L * K + k0,  &Bs[2048 + t * 8]);
        gload_lds16(gB0 + 128L * K + k0, &Bs[4096 + t * 8]);
        __syncthreads();

        bf16x8 af[4], bfr[3];
#pragma unroll
        for (int m = 0; m < 4; ++m)
            af[m] = *(const bf16x8*)&As[m * 512 + fbase];
#pragma unroll
        for (int n = 0; n < 3; ++n)
            bfr[n] = *(const bf16x8*)&Bs[(wave * 3 + n) * 512 + fbase];
#pragma unroll
        for (int m = 0; m < 4; ++m)
#pragma unroll
            for (int n = 0; n < 3; ++n)
                acc[m][n] = __builtin_amdgcn_mfma_f32_16x16x32_bf16(
                    af[m], bfr[n], acc[m][n], 0, 0, 0);
        __syncthreads();
    }

    // C tile -> LDS as bf16 (+bias), padded rows
#pragma unroll
    for (int n = 0; n < 3; ++n) {
        const int cl = wc + n * 16 + fr;
        const float bv = bias[bcol + cl];
#pragma unroll
        for (int m = 0; m < 4; ++m) {
            const int rl = m * 16 + (lane >> 4) * 4;
#pragma unroll
            for (int j = 0; j < 4; ++j)
                smem[(rl + j) * CLS + cl] = f2bf_r(acc[m][n][j] + bv);
        }
    }
    __syncthreads();

    // RQS: 64 rows x 8 dims = 512 (b,d) pairs; 2 per thread
    const int dbase = blockIdx.x * 8;
#pragma unroll
    for (int pi = 0; pi < 2; ++pi) {
        const int p  = t + pi * 256;
        const int bl = p >> 3;
        const int dl = p & 7;
        const u16* pp = &smem[bl * CLS + dl * 24];
        bf16x8 v0 = *(const bf16x8*)(pp);        // widths
        bf16x8 v1 = *(const bf16x8*)(pp + 8);    // heights
        bf16x8 v2 = *(const bf16x8*)(pp + 16);   // raw derivs (7) + pad(=0)

        // softmax WITHOUT max-subtraction (|params| ~ O(1), exp can't overflow)
        float w[8], h[8];
        float sw = 0.f, sh = 0.f;
#pragma unroll
        for (int i = 0; i < 8; ++i) { w[i] = __expf((float)v0[i]); sw += w[i]; }
#pragma unroll
        for (int i = 0; i < 8; ++i) { h[i] = __expf((float)v1[i]); sh += h[i]; }
        const float rw = 0.992f * rcpf(sw);
        const float rh = 0.992f * rcpf(sh);
#pragma unroll
        for (int i = 0; i < 8; ++i) w[i] = fmaf(w[i], rw, 0.001f);
#pragma unroll
        for (int i = 0; i < 8; ++i) h[i] = fmaf(h[i], rh, 0.001f);

        const long b = brow + bl;
        const int  d = dbase + dl;
        float xin = x[b * 64 + d];
        xin = fminf(fmaxf(xin, 0.f), 1.f);

        // bin select; pick RAW deriv params, softplus only the 2 selected
        float x_k = 0.f, y_k = 0.f, w_k = w[0], h_k = h[0];
        float rk = 0.f, rk1 = (float)v2[0];
        bool isfirst = true, islast = false;
        float cw = 0.f, ch = 0.f;
#pragma unroll
        for (int i = 1; i < 8; ++i) {
            cw += w[i - 1]; ch += h[i - 1];
            if (cw < xin) {
                x_k = cw; y_k = ch; w_k = w[i]; h_k = h[i];
                rk = (float)v2[i - 1];
                rk1 = (i < 7) ? (float)v2[i] : 0.f;
                isfirst = false; islast = (i == 7);
            }
        }
        float sp_k  = __logf(1.f + __expf(rk));
        float sp_k1 = __logf(1.f + __expf(rk1));
        float d_k  = isfirst ? 1.f : sp_k  + 0.001f;
        float d_k1 = islast  ? 1.f : sp_k1 + 0.001f;

        const float inv_wk = rcpf(w_k);
        const float s   = h_k * inv_wk;
        const float th  = (xin - x_k) * inv_wk;
        const float omt = 1.f - th;
        const float t1t = th * omt;
        const float den = fmaf(d_k + d_k1 - 2.f * s, t1t, s);
        const float num = fmaf(s * th, th, d_k * t1t);
        const float out = fmaf(h_k * num, rcpf(den + 1e-6f), y_k);
        const float nom = s * s * fmaf(d_k1 * th, th, fmaf(2.f * s, t1t, d_k * omt * omt));
        const float logdet = __logf(nom) - __logf(fmaf(den, den, 1e-6f));

        z[b * 64 + d]   = out;
        ldp[b * 64 + d] = logdet;
    }
}

__global__ __launch_bounds__(256) void ld_reduce(
    const float* __restrict__ ldp, float* __restrict__ ld)
{
    const int b = blockIdx.x * 4 + (threadIdx.x >> 6);
    const int lane = threadIdx.x & 63;
    float r = ldp[(long)b * 64 + lane];
#pragma unroll
    for (int off = 32; off; off >>= 1) r += __shfl_xor(r, off, 64);
    if (lane == 0) ld[b] = r;
}

__global__ void cvt_x_bf16(const float* __restrict__ in, u16* __restrict__ out, long n) {
    long i = (long)blockIdx.x * blockDim.x + threadIdx.x;
    long stride = (long)gridDim.x * blockDim.x;
    for (; i < n; i += stride) out[i] = f2bf_r(in[i]);
}

__global__ void transpose_w_bf16(const float* __restrict__ W, u16* __restrict__ WT,
                                 int K, int N) {
    long total = (long)N * K;
    long i = (long)blockIdx.x * blockDim.x + threadIdx.x;
    long stride = (long)gridDim.x * blockDim.x;
    for (; i < total; i += stride) {
        int n = (int)(i / K), k = (int)(i % K);
        WT[i] = f2bf_r(W[(long)k * N + n]);
    }
}

__global__ void transpose_w2_bf16(const float* __restrict__ W, u16* __restrict__ WT, int K) {
    long total = 1536L * K;
    long i = (long)blockIdx.x * blockDim.x + threadIdx.x;
    long stride = (long)gridDim.x * blockDim.x;
    for (; i < total; i += stride) {
        int npad = (int)(i / K), k = (int)(i % K);
        int g = npad / 24, r = npad % 24;
        float v = (r < 23) ? W[(long)k * 1472 + g * 23 + r] : 0.f;
        WT[i] = f2bf_r(v);
    }
}

__global__ void pad_bias2(const float* __restrict__ b2, float* __restrict__ b2p) {
    int c = blockIdx.x * 256 + threadIdx.x;
    if (c < 1536) {
        int g = c / 24, r = c % 24;
        b2p[c] = (r < 23) ? b2[g * 23 + r] : 0.f;
    }
}

__global__ void fill_fail(float* __restrict__ out, long n) {
    long i = (long)blockIdx.x * blockDim.x + threadIdx.x;
    long stride = (long)gridDim.x * blockDim.x;
    for (; i < n; i += stride) out[i] = -1.0f;
}

extern "C" void kernel_launch(void* const* d_in, const int* in_sizes, int n_in,
                              void* d_out, int out_size, void* d_ws, size_t ws_size,
                              hipStream_t stream)
{
    const float* x  = (const float*)d_in[0];
    const float* W0 = (const float*)d_in[1];
    const float* b0 = (const float*)d_in[2];
    const float* W1 = (const float*)d_in[3];
    const float* b1 = (const float*)d_in[4];
    const float* W2 = (const float*)d_in[5];
    const float* b2 = (const float*)d_in[6];
    const int B = in_sizes[0] / 64;   // 65536
    const int D = 64, H = 512, NP = 1536;

    char* ws = (char*)d_ws;
    size_t off = 0;
    u16* W0T = (u16*)(ws + off); off += (size_t)H * D * 2;
    u16* W1T = (u16*)(ws + off); off += (size_t)H * H * 2;
    u16* W2T = (u16*)(ws + off); off += (size_t)NP * H * 2;
    float* b2p = (float*)(ws + off); off += (size_t)NP * 4;
    off = (off + 255) & ~(size_t)255;
    u16*   h1  = (u16*)(ws + off);
    float* ldp = (float*)(ws + off);
    off += (size_t)B * H * 2;
    u16* xb = (u16*)(ws + off);
    u16* h2 = (u16*)(ws + off);
    off += (size_t)B * H * 2;
    size_t need = off;

    float* zout  = (float*)d_out;
    float* ldout = zout + (size_t)B * D;

    if (ws_size < need) {
        fill_fail<<<2048, 256, 0, stream>>>(zout, (long)out_size);
        return;
    }

    cvt_x_bf16<<<2048, 256, 0, stream>>>(x, xb, (long)B * D);
    transpose_w_bf16<<<128, 256, 0, stream>>>(W0, W0T, D, H);
    transpose_w_bf16<<<1024, 256, 0, stream>>>(W1, W1T, H, H);
    transpose_w2_bf16<<<3072, 256, 0, stream>>>(W2, W2T, H);
    pad_bias2<<<6, 256, 0, stream>>>(b2, b2p);

    dim3 g12(H / BN, B / BM);          // (4, 512)
    gemm_bt<64, 1><<<g12, 256, 0, stream>>>(xb, W0T, b0, h1, B, H);
    gemm_bt<512, 1><<<g12, 256, 0, stream>>>(h1, W1T, b1, h2, B, H);

    dim3 g3(NP / FBN, B / FBM);        // (8, 1024)
    gemm3_rqs<512><<<g3, 256, 0, stream>>>(h2, W2T, b2p, x, zout, ldp);

    ld_reduce<<<B / 4, 256, 0, stream>>>(ldp, ldout);
}

// Round 5
// 262.673 us; speedup vs baseline: 1.3871x; 1.3871x over previous
//
#include <hip/hip_runtime.h>

typedef unsigned short u16;
typedef __bf16 bf16x8 __attribute__((ext_vector_type(8)));
typedef float f32x4 __attribute__((ext_vector_type(4)));

// cheap float->bf16: round via +0x8000 then truncate (<=1ulp vs RNE)
__device__ __forceinline__ u16 f2bf_r(float f) {
    union { float f; unsigned u; } v; v.f = f;
    return (u16)((v.u + 0x8000u) >> 16);
}
__device__ __forceinline__ float rcpf(float x) { return __builtin_amdgcn_rcpf(x); }

__device__ __forceinline__ void gload_lds16(const u16* g, u16* l) {
    __builtin_amdgcn_global_load_lds(
        (const __attribute__((address_space(1))) void*)g,
        (__attribute__((address_space(3))) void*)l,
        16, 0, 0);
}

// ---------------------------------------------------------------------------
// Staging (per 64-row group, 256 threads): thread t loads row t>>2, k-granule
// gsw=(t&3)^((t>>3)&3) -> 4 consecutive lanes = one aligned 64B line (coalesced).
// LDS dest linear (chunk t). Fragment read: lane l, group m reads chunk
// (16m+fr)*4 + (g ^ ((fr>>1)&3)), fr=l&15, g=l>>4 -> 2-way bank spread (free).
// ---------------------------------------------------------------------------

#define BM 128
#define BN 128
#define BK 32

template<int K, int RELU>
__global__ __launch_bounds__(256) void gemm_bt(
    const u16* __restrict__ A, const u16* __restrict__ BT,
    const float* __restrict__ bias, u16* __restrict__ C,
    int M, int N)
{
    __shared__ u16 smem[2 * 8192];           // 2 buffers x (As 4096 + Bs 4096) u16
    const int t = threadIdx.x;
    const int lane = t & 63;
    const int wave = t >> 6;
    const int wr = (wave >> 1) * 64;
    const int wc = (wave & 1) * 64;
    const long brow = (long)blockIdx.y * BM;
    const long bcol = (long)blockIdx.x * BN;

    const int sr = t >> 2;                            // row within 64-row group
    const int sc = ((t & 3) ^ ((t >> 3) & 3)) * 8;    // swizzled k-granule
    const u16* gA0 = A + (brow + sr) * (long)K + sc;
    const u16* gA1 = gA0 + 64L * K;
    const u16* gB0 = BT + (bcol + sr) * (long)K + sc;
    const u16* gB1 = gB0 + 64L * K;

    f32x4 acc[4][4] = {};
    const int fr = lane & 15;
    const int fbase = fr * 32 + (((lane >> 4) ^ ((fr >> 1) & 3)) * 8);

    auto STAGE = [&](int buf, int k0) {
        u16* As = &smem[buf * 8192];
        u16* Bs = As + 4096;
        gload_lds16(gA0 + k0, &As[t * 8]);
        gload_lds16(gA1 + k0, &As[2048 + t * 8]);
        gload_lds16(gB0 + k0, &Bs[t * 8]);
        gload_lds16(gB1 + k0, &Bs[2048 + t * 8]);
    };
    auto COMPUTE = [&](int buf) {
        const u16* As = &smem[buf * 8192];
        const u16* Bs = As + 4096;
        bf16x8 af[4], bfr[4];
#pragma unroll
        for (int m = 0; m < 4; ++m)
            af[m] = *(const bf16x8*)&As[wr * 32 + m * 512 + fbase];
#pragma unroll
        for (int n = 0; n < 4; ++n)
            bfr[n] = *(const bf16x8*)&Bs[wc * 32 + n * 512 + fbase];
#pragma unroll
        for (int m = 0; m < 4; ++m)
#pragma unroll
            for (int n = 0; n < 4; ++n)
                acc[m][n] = __builtin_amdgcn_mfma_f32_16x16x32_bf16(
                    af[m], bfr[n], acc[m][n], 0, 0, 0);
    };

    STAGE(0, 0);
    __syncthreads();
    int cur = 0;
#pragma unroll
    for (int k0 = BK; k0 < K; k0 += BK) {
        STAGE(cur ^ 1, k0);      // prefetch next tile (latency hides under MFMA)
        COMPUTE(cur);
        __syncthreads();
        cur ^= 1;
    }
    COMPUTE(cur);

#pragma unroll
    for (int n = 0; n < 4; ++n) {
        const long col = bcol + wc + n * 16 + fr;
        const float bv = bias[col];
#pragma unroll
        for (int m = 0; m < 4; ++m) {
            const long row = brow + wr + m * 16 + (lane >> 4) * 4;
#pragma unroll
            for (int j = 0; j < 4; ++j) {
                float v = acc[m][n][j] + bv;
                if (RELU) v = fmaxf(v, 0.f);
                C[(row + j) * (long)N + col] = f2bf_r(v);
            }
        }
    }
}

// ---- fused GEMM3 (64x192 tile) + RQS spline ----
#define FBM 64
#define FBN 192
#define FBK 32
#define CLS 200   // padded LDS row stride (u16) for the C tile

template<int K>
__global__ __launch_bounds__(256) void gemm3_rqs(
    const u16* __restrict__ A,       // h2: B x K bf16
    const u16* __restrict__ BT,      // W2T padded: 1536 x K bf16
    const float* __restrict__ bias,  // b2p: 1536
    const float* __restrict__ x,     // B x 64 fp32
    float* __restrict__ z,           // B x 64 fp32
    float* __restrict__ ldp)         // B x 64 fp32 partial logdet
{
    __shared__ u16 smem[2 * 8192];           // 32 KB: 2 x (As 2048 + Bs 6144)
    const int t = threadIdx.x;
    const int lane = t & 63;
    const int wave = t >> 6;
    const int wc = wave * 48;                // 4 waves x 48 cols
    const long brow = (long)blockIdx.y * FBM;
    const int bcol = blockIdx.x * FBN;

    const int sr = t >> 2;
    const int sc = ((t & 3) ^ ((t >> 3) & 3)) * 8;
    const u16* gA0 = A + (brow + sr) * (long)K + sc;
    const u16* gB0 = BT + (long)(bcol + sr) * K + sc;

    f32x4 acc[4][3] = {};
    const int fr = lane & 15;
    const int fbase = fr * 32 + (((lane >> 4) ^ ((fr >> 1) & 3)) * 8);

    auto STAGE = [&](int buf, int k0) {
        u16* As = &smem[buf * 8192];
        u16* Bs = As + 2048;
        gload_lds16(gA0 + k0,            &As[t * 8]);
        gload_lds16(gB0 + k0,            &Bs[t * 8]);
        gload_lds16(gB0 + 64L * K + k0,  &Bs[2048 + t * 8]);
        gload_lds16(gB0 + 128L * K + k0, &Bs[4096 + t * 8]);
    };
    auto COMPUTE = [&](int buf) {
        const u16* As = &smem[buf * 8192];
        const u16* Bs = As + 2048;
        bf16x8 af[4], bfr[3];
#pragma unroll
        for (int m = 0; m < 4; ++m)
            af[m] = *(const bf16x8*)&As[m * 512 + fbase];
#pragma unroll
        for (int n = 0; n < 3; ++n)
            bfr[n] = *(const bf16x8*)&Bs[(wave * 3 + n) * 512 + fbase];
#pragma unroll
        for (int m = 0; m < 4; ++m)
#pragma unroll
            for (int n = 0; n < 3; ++n)
                acc[m][n] = __builtin_amdgcn_mfma_f32_16x16x32_bf16(
                    af[m], bfr[n], acc[m][n], 0, 0, 0);
    };

    STAGE(0, 0);
    __syncthreads();
    int cur = 0;
#pragma unroll
    for (int k0 = FBK; k0 < K; k0 += FBK) {
        STAGE(cur ^ 1, k0);
        COMPUTE(cur);
        __syncthreads();
        cur ^= 1;
    }
    COMPUTE(cur);
    __syncthreads();                          // before aliasing smem with C tile

    // C tile -> LDS as bf16 (+bias), padded rows (64 x CLS = 12800 u16 fits)
#pragma unroll
    for (int n = 0; n < 3; ++n) {
        const int cl = wc + n * 16 + fr;
        const float bv = bias[bcol + cl];
#pragma unroll
        for (int m = 0; m < 4; ++m) {
            const int rl = m * 16 + (lane >> 4) * 4;
#pragma unroll
            for (int j = 0; j < 4; ++j)
                smem[(rl + j) * CLS + cl] = f2bf_r(acc[m][n][j] + bv);
        }
    }
    __syncthreads();

    // RQS: 64 rows x 8 dims = 512 (b,d) pairs; 2 per thread
    const int dbase = blockIdx.x * 8;
#pragma unroll
    for (int pi = 0; pi < 2; ++pi) {
        const int p  = t + pi * 256;
        const int bl = p >> 3;
        const int dl = p & 7;
        const u16* pp = &smem[bl * CLS + dl * 24];
        bf16x8 v0 = *(const bf16x8*)(pp);        // widths
        bf16x8 v1 = *(const bf16x8*)(pp + 8);    // heights
        bf16x8 v2 = *(const bf16x8*)(pp + 16);   // raw derivs (7) + pad(=0)

        // softmax WITHOUT max-subtraction (|params| ~ O(1), exp can't overflow)
        float w[8], h[8];
        float sw = 0.f, sh = 0.f;
#pragma unroll
        for (int i = 0; i < 8; ++i) { w[i] = __expf((float)v0[i]); sw += w[i]; }
#pragma unroll
        for (int i = 0; i < 8; ++i) { h[i] = __expf((float)v1[i]); sh += h[i]; }
        const float rw = 0.992f * rcpf(sw);
        const float rh = 0.992f * rcpf(sh);
#pragma unroll
        for (int i = 0; i < 8; ++i) w[i] = fmaf(w[i], rw, 0.001f);
#pragma unroll
        for (int i = 0; i < 8; ++i) h[i] = fmaf(h[i], rh, 0.001f);

        const long b = brow + bl;
        const int  d = dbase + dl;
        float xin = x[b * 64 + d];
        xin = fminf(fmaxf(xin, 0.f), 1.f);

        // bin select; pick RAW deriv params, softplus only the 2 selected
        float x_k = 0.f, y_k = 0.f, w_k = w[0], h_k = h[0];
        float rk = 0.f, rk1 = (float)v2[0];
        bool isfirst = true, islast = false;
        float cw = 0.f, ch = 0.f;
#pragma unroll
        for (int i = 1; i < 8; ++i) {
            cw += w[i - 1]; ch += h[i - 1];
            if (cw < xin) {
                x_k = cw; y_k = ch; w_k = w[i]; h_k = h[i];
                rk = (float)v2[i - 1];
                rk1 = (i < 7) ? (float)v2[i] : 0.f;
                isfirst = false; islast = (i == 7);
            }
        }
        float sp_k  = __logf(1.f + __expf(rk));
        float sp_k1 = __logf(1.f + __expf(rk1));
        float d_k  = isfirst ? 1.f : sp_k  + 0.001f;
        float d_k1 = islast  ? 1.f : sp_k1 + 0.001f;

        const float inv_wk = rcpf(w_k);
        const float s   = h_k * inv_wk;
        const float th  = (xin - x_k) * inv_wk;
        const float omt = 1.f - th;
        const float t1t = th * omt;
        const float den = fmaf(d_k + d_k1 - 2.f * s, t1t, s);
        const float num = fmaf(s * th, th, d_k * t1t);
        const float out = fmaf(h_k * num, rcpf(den + 1e-6f), y_k);
        const float nom = s * s * fmaf(d_k1 * th, th, fmaf(2.f * s, t1t, d_k * omt * omt));
        const float logdet = __logf(nom) - __logf(fmaf(den, den, 1e-6f));

        z[b * 64 + d]   = out;
        ldp[b * 64 + d] = logdet;
    }
}

__global__ __launch_bounds__(256) void ld_reduce(
    const float* __restrict__ ldp, float* __restrict__ ld)
{
    const int b = blockIdx.x * 4 + (threadIdx.x >> 6);
    const int lane = threadIdx.x & 63;
    float r = ldp[(long)b * 64 + lane];
#pragma unroll
    for (int off = 32; off; off >>= 1) r += __shfl_xor(r, off, 64);
    if (lane == 0) ld[b] = r;
}

__global__ void cvt_x_bf16(const float* __restrict__ in, u16* __restrict__ out, long n) {
    long i = (long)blockIdx.x * blockDim.x + threadIdx.x;
    long stride = (long)gridDim.x * blockDim.x;
    for (; i < n; i += stride) out[i] = f2bf_r(in[i]);
}

__global__ void transpose_w_bf16(const float* __restrict__ W, u16* __restrict__ WT,
                                 int K, int N) {
    long total = (long)N * K;
    long i = (long)blockIdx.x * blockDim.x + threadIdx.x;
    long stride = (long)gridDim.x * blockDim.x;
    for (; i < total; i += stride) {
        int n = (int)(i / K), k = (int)(i % K);
        WT[i] = f2bf_r(W[(long)k * N + n]);
    }
}

__global__ void transpose_w2_bf16(const float* __restrict__ W, u16* __restrict__ WT, int K) {
    long total = 1536L * K;
    long i = (long)blockIdx.x * blockDim.x + threadIdx.x;
    long stride = (long)gridDim.x * blockDim.x;
    for (; i < total; i += stride) {
        int npad = (int)(i / K), k = (int)(i % K);
        int g = npad / 24, r = npad % 24;
        float v = (r < 23) ? W[(long)k * 1472 + g * 23 + r] : 0.f;
        WT[i] = f2bf_r(v);
    }
}

__global__ void pad_bias2(const float* __restrict__ b2, float* __restrict__ b2p) {
    int c = blockIdx.x * 256 + threadIdx.x;
    if (c < 1536) {
        int g = c / 24, r = c % 24;
        b2p[c] = (r < 23) ? b2[g * 23 + r] : 0.f;
    }
}

__global__ void fill_fail(float* __restrict__ out, long n) {
    long i = (long)blockIdx.x * blockDim.x + threadIdx.x;
    long stride = (long)gridDim.x * blockDim.x;
    for (; i < n; i += stride) out[i] = -1.0f;
}

extern "C" void kernel_launch(void* const* d_in, const int* in_sizes, int n_in,
                              void* d_out, int out_size, void* d_ws, size_t ws_size,
                              hipStream_t stream)
{
    const float* x  = (const float*)d_in[0];
    const float* W0 = (const float*)d_in[1];
    const float* b0 = (const float*)d_in[2];
    const float* W1 = (const float*)d_in[3];
    const float* b1 = (const float*)d_in[4];
    const float* W2 = (const float*)d_in[5];
    const float* b2 = (const float*)d_in[6];
    const int B = in_sizes[0] / 64;   // 65536
    const int D = 64, H = 512, NP = 1536;

    char* ws = (char*)d_ws;
    size_t off = 0;
    u16* W0T = (u16*)(ws + off); off += (size_t)H * D * 2;
    u16* W1T = (u16*)(ws + off); off += (size_t)H * H * 2;
    u16* W2T = (u16*)(ws + off); off += (size_t)NP * H * 2;
    float* b2p = (float*)(ws + off); off += (size_t)NP * 4;
    off = (off + 255) & ~(size_t)255;
    u16*   h1  = (u16*)(ws + off);
    float* ldp = (float*)(ws + off);
    off += (size_t)B * H * 2;
    u16* xb = (u16*)(ws + off);
    u16* h2 = (u16*)(ws + off);
    off += (size_t)B * H * 2;
    size_t need = off;

    float* zout  = (float*)d_out;
    float* ldout = zout + (size_t)B * D;

    if (ws_size < need) {
        fill_fail<<<2048, 256, 0, stream>>>(zout, (long)out_size);
        return;
    }

    cvt_x_bf16<<<2048, 256, 0, stream>>>(x, xb, (long)B * D);
    transpose_w_bf16<<<128, 256, 0, stream>>>(W0, W0T, D, H);
    transpose_w_bf16<<<1024, 256, 0, stream>>>(W1, W1T, H, H);
    transpose_w2_bf16<<<3072, 256, 0, stream>>>(W2, W2T, H);
    pad_bias2<<<6, 256, 0, stream>>>(b2, b2p);

    dim3 g12(H / BN, B / BM);          // (4, 512)
    gemm_bt<64, 1><<<g12, 256, 0, stream>>>(xb, W0T, b0, h1, B, H);
    gemm_bt<512, 1><<<g12, 256, 0, stream>>>(h1, W1T, b1, h2, B, H);

    dim3 g3(NP / FBN, B / FBM);        // (8, 1024)
    gemm3_rqs<512><<<g3, 256, 0, stream>>>(h2, W2T, b2p, x, zout, ldp);

    ld_reduce<<<B / 4, 256, 0, stream>>>(ldp, ldout);
}

// Round 6
// 210.249 us; speedup vs baseline: 1.7330x; 1.2493x over previous
//
#include <hip/hip_runtime.h>

typedef unsigned short u16;
typedef __bf16 bf16x8 __attribute__((ext_vector_type(8)));
typedef float f32x4 __attribute__((ext_vector_type(4)));

// cheap float->bf16: round via +0x8000 then truncate (<=1ulp vs RNE)
__device__ __forceinline__ u16 f2bf_r(float f) {
    union { float f; unsigned u; } v; v.f = f;
    return (u16)((v.u + 0x8000u) >> 16);
}
__device__ __forceinline__ float rcpf(float x) { return __builtin_amdgcn_rcpf(x); }

__device__ __forceinline__ void gload_lds16(const u16* g, u16* l) {
    __builtin_amdgcn_global_load_lds(
        (const __attribute__((address_space(1))) void*)g,
        (__attribute__((address_space(3))) void*)l,
        16, 0, 0);
}

// ---------------------------------------------------------------------------
// Staging: thread t loads row t>>2, k-granule (t&3)^((t>>3)&3) -> 4 adjacent
// lanes read one aligned 64B line (coalesced); LDS dest linear (chunk t).
// Fragment read offset: fr*32 + ((g ^ ((fr>>1)&3))*8)  -> 2-way bank alias (free).
// K-loop: 3 LDS buffers, counted s_waitcnt vmcnt(L) + raw s_barrier; stage k+2
// issued AFTER the barrier (all waves finished compute k-1 -> its buffer free).
// XCD swizzle: block n -> (brow=(n&7)+8*((n>>3)/NBX), bcol=(n>>3)%NBX) so the
// NBX col-siblings of a brow share one XCD's L2 (A-tile fetched once).
// ---------------------------------------------------------------------------

#define BM 128
#define BN 128
#define BK 32

template<int K, int RELU, int NBX>
__global__ __launch_bounds__(256) void gemm_bt(
    const u16* __restrict__ A, const u16* __restrict__ BT,
    const float* __restrict__ bias, u16* __restrict__ C,
    int M, int N)
{
    constexpr int NS = K / BK;
    __shared__ u16 smem[3 * 8192];           // 48 KB: 3 x (As 4096 + Bs 4096)
    const int t = threadIdx.x;
    const int lane = t & 63;
    const int wave = t >> 6;
    const int wr = (wave >> 1) * 64;
    const int wc = (wave & 1) * 64;

    const int nlin = blockIdx.x;
    const int jj = nlin >> 3;
    const long brow = (long)((nlin & 7) + 8 * (jj / NBX)) * BM;
    const long bcol = (long)(jj % NBX) * BN;

    const int sr = t >> 2;
    const int sc = ((t & 3) ^ ((t >> 3) & 3)) * 8;
    const u16* gA0 = A + (brow + sr) * (long)K + sc;
    const u16* gA1 = gA0 + 64L * K;
    const u16* gB0 = BT + (bcol + sr) * (long)K + sc;
    const u16* gB1 = gB0 + 64L * K;

    f32x4 acc[4][4] = {};
    const int fr = lane & 15;
    const int fbase = fr * 32 + (((lane >> 4) ^ ((fr >> 1) & 3)) * 8);

    auto STAGE = [&](int buf, int k0) {
        u16* As = &smem[buf * 8192];
        u16* Bs = As + 4096;
        gload_lds16(gA0 + k0, &As[t * 8]);
        gload_lds16(gA1 + k0, &As[2048 + t * 8]);
        gload_lds16(gB0 + k0, &Bs[t * 8]);
        gload_lds16(gB1 + k0, &Bs[2048 + t * 8]);
    };
    auto COMPUTE = [&](int buf) {
        const u16* As = &smem[buf * 8192];
        const u16* Bs = As + 4096;
        bf16x8 af[4], bfr[4];
#pragma unroll
        for (int m = 0; m < 4; ++m)
            af[m] = *(const bf16x8*)&As[wr * 32 + m * 512 + fbase];
#pragma unroll
        for (int n = 0; n < 4; ++n)
            bfr[n] = *(const bf16x8*)&Bs[wc * 32 + n * 512 + fbase];
#pragma unroll
        for (int m = 0; m < 4; ++m)
#pragma unroll
            for (int n = 0; n < 4; ++n)
                acc[m][n] = __builtin_amdgcn_mfma_f32_16x16x32_bf16(
                    af[m], bfr[n], acc[m][n], 0, 0, 0);
    };

    STAGE(0, 0);
    STAGE(1, BK);
#pragma unroll
    for (int i = 0; i < NS; ++i) {
        if (i < NS - 1) asm volatile("s_waitcnt vmcnt(4)" ::: "memory");
        else            asm volatile("s_waitcnt vmcnt(0)" ::: "memory");
        __builtin_amdgcn_s_barrier();
        __builtin_amdgcn_sched_barrier(0);
        if (i + 2 < NS) STAGE((i + 2) % 3, (i + 2) * BK);
        COMPUTE(i % 3);
    }

#pragma unroll
    for (int n = 0; n < 4; ++n) {
        const long col = bcol + wc + n * 16 + fr;
        const float bv = bias[col];
#pragma unroll
        for (int m = 0; m < 4; ++m) {
            const long row = brow + wr + m * 16 + (lane >> 4) * 4;
#pragma unroll
            for (int j = 0; j < 4; ++j) {
                float v = acc[m][n][j] + bv;
                if (RELU) v = fmaxf(v, 0.f);
                C[(row + j) * (long)N + col] = f2bf_r(v);
            }
        }
    }
}

// ---- fused GEMM3 (128x192 tile, 2x2 wave grid, wave=64x96) + RQS spline ----
#define FBM 128
#define FBN 192
#define FBK 32
#define CLS 200   // padded LDS row stride (u16) for the C tile

template<int K>
__global__ __launch_bounds__(256) void gemm3_rqs(
    const u16* __restrict__ A,       // h2: B x K bf16
    const u16* __restrict__ BT,      // W2T padded: 1536 x K bf16
    const float* __restrict__ bias,  // b2p: 1536
    const float* __restrict__ x,     // B x 64 fp32
    float* __restrict__ z,           // B x 64 fp32
    float* __restrict__ ldp)         // B x 64 fp32 partial logdet
{
    constexpr int NS = K / FBK;
    __shared__ u16 smem[3 * 10240];          // 60 KB: 3 x (As 4096 + Bs 6144)
                                             // C-tile (128*200=25600 u16) aliases
    const int t = threadIdx.x;
    const int lane = t & 63;
    const int wave = t >> 6;
    const int wr = (wave >> 1) * 64;         // 2x2 wave grid: 64 rows x 96 cols
    const int wc = (wave & 1) * 96;

    const int nlin = blockIdx.x;             // 4096 blocks, NBX=8
    const int jj = nlin >> 3;
    const long brow = (long)((nlin & 7) + 8 * (jj >> 3)) * FBM;
    const int bx = jj & 7;
    const int bcol = bx * FBN;

    const int sr = t >> 2;
    const int sc = ((t & 3) ^ ((t >> 3) & 3)) * 8;
    const u16* gA0 = A + (brow + sr) * (long)K + sc;
    const u16* gB0 = BT + (long)(bcol + sr) * K + sc;

    f32x4 acc[4][6] = {};
    const int fr = lane & 15;
    const int gsel = ((lane >> 4) ^ ((fr >> 1) & 3)) * 8;
    const int fbase = fr * 32 + gsel;

    // B fragment offsets (wc=96 straddles 64-row regions; precompute, static idx)
    int b_off[6];
#pragma unroll
    for (int n = 0; n < 6; ++n) {
        int rb = wc + n * 16 + fr;
        b_off[n] = (rb >> 6) * 2048 + (rb & 63) * 32 + gsel;
    }

    auto STAGE = [&](int buf, int k0) {
        u16* As = &smem[buf * 10240];
        u16* Bs = As + 4096;
        gload_lds16(gA0 + k0,            &As[t * 8]);
        gload_lds16(gA0 + 64L * K + k0,  &As[2048 + t * 8]);
        gload_lds16(gB0 + k0,            &Bs[t * 8]);
        gload_lds16(gB0 + 64L * K + k0,  &Bs[2048 + t * 8]);
        gload_lds16(gB0 + 128L * K + k0, &Bs[4096 + t * 8]);
    };
    auto COMPUTE = [&](int buf) {
        const u16* As = &smem[buf * 10240];
        const u16* Bs = As + 4096;
        bf16x8 af[4], bfr[6];
#pragma unroll
        for (int m = 0; m < 4; ++m)
            af[m] = *(const bf16x8*)&As[wr * 32 + m * 512 + fbase];
#pragma unroll
        for (int n = 0; n < 6; ++n)
            bfr[n] = *(const bf16x8*)&Bs[b_off[n]];
#pragma unroll
        for (int m = 0; m < 4; ++m)
#pragma unroll
            for (int n = 0; n < 6; ++n)
                acc[m][n] = __builtin_amdgcn_mfma_f32_16x16x32_bf16(
                    af[m], bfr[n], acc[m][n], 0, 0, 0);
    };

    STAGE(0, 0);
    STAGE(1, FBK);
#pragma unroll
    for (int i = 0; i < NS; ++i) {
        if (i < NS - 1) asm volatile("s_waitcnt vmcnt(5)" ::: "memory");
        else            asm volatile("s_waitcnt vmcnt(0)" ::: "memory");
        __builtin_amdgcn_s_barrier();
        __builtin_amdgcn_sched_barrier(0);
        if (i + 2 < NS) STAGE((i + 2) % 3, (i + 2) * FBK);
        COMPUTE(i % 3);
    }
    __syncthreads();                          // before aliasing smem with C tile

    // C tile -> LDS as bf16 (+bias), padded rows (128 x 200 = 25600 u16)
#pragma unroll
    for (int n = 0; n < 6; ++n) {
        const int cl = wc + n * 16 + fr;
        const float bv = bias[bcol + cl];
#pragma unroll
        for (int m = 0; m < 4; ++m) {
            const int rl = wr + m * 16 + (lane >> 4) * 4;
#pragma unroll
            for (int j = 0; j < 4; ++j)
                smem[(rl + j) * CLS + cl] = f2bf_r(acc[m][n][j] + bv);
        }
    }
    __syncthreads();

    // RQS: 128 rows x 8 dims = 1024 (b,d) pairs; 4 per thread
    const int dbase = bx * 8;
#pragma unroll
    for (int pi = 0; pi < 4; ++pi) {
        const int p  = t + pi * 256;
        const int bl = p >> 3;
        const int dl = p & 7;
        const u16* pp = &smem[bl * CLS + dl * 24];
        bf16x8 v0 = *(const bf16x8*)(pp);        // widths
        bf16x8 v1 = *(const bf16x8*)(pp + 8);    // heights
        bf16x8 v2 = *(const bf16x8*)(pp + 16);   // raw derivs (7) + pad(=0)

        float w[8], h[8];
        float sw = 0.f, sh = 0.f;
#pragma unroll
        for (int i = 0; i < 8; ++i) { w[i] = __expf((float)v0[i]); sw += w[i]; }
#pragma unroll
        for (int i = 0; i < 8; ++i) { h[i] = __expf((float)v1[i]); sh += h[i]; }
        const float rw = 0.992f * rcpf(sw);
        const float rh = 0.992f * rcpf(sh);
#pragma unroll
        for (int i = 0; i < 8; ++i) w[i] = fmaf(w[i], rw, 0.001f);
#pragma unroll
        for (int i = 0; i < 8; ++i) h[i] = fmaf(h[i], rh, 0.001f);

        const long b = brow + bl;
        const int  d = dbase + dl;
        float xin = x[b * 64 + d];
        xin = fminf(fmaxf(xin, 0.f), 1.f);

        float x_k = 0.f, y_k = 0.f, w_k = w[0], h_k = h[0];
        float rk = 0.f, rk1 = (float)v2[0];
        bool isfirst = true, islast = false;
        float cw = 0.f, ch = 0.f;
#pragma unroll
        for (int i = 1; i < 8; ++i) {
            cw += w[i - 1]; ch += h[i - 1];
            if (cw < xin) {
                x_k = cw; y_k = ch; w_k = w[i]; h_k = h[i];
                rk = (float)v2[i - 1];
                rk1 = (i < 7) ? (float)v2[i] : 0.f;
                isfirst = false; islast = (i == 7);
            }
        }
        float sp_k  = __logf(1.f + __expf(rk));
        float sp_k1 = __logf(1.f + __expf(rk1));
        float d_k  = isfirst ? 1.f : sp_k  + 0.001f;
        float d_k1 = islast  ? 1.f : sp_k1 + 0.001f;

        const float inv_wk = rcpf(w_k);
        const float s   = h_k * inv_wk;
        const float th  = (xin - x_k) * inv_wk;
        const float omt = 1.f - th;
        const float t1t = th * omt;
        const float den = fmaf(d_k + d_k1 - 2.f * s, t1t, s);
        const float num = fmaf(s * th, th, d_k * t1t);
        const float out = fmaf(h_k * num, rcpf(den + 1e-6f), y_k);
        const float nom = s * s * fmaf(d_k1 * th, th, fmaf(2.f * s, t1t, d_k * omt * omt));
        const float logdet = __logf(nom) - __logf(fmaf(den, den, 1e-6f));

        z[b * 64 + d]   = out;
        ldp[b * 64 + d] = logdet;
    }
}

__global__ __launch_bounds__(256) void ld_reduce(
    const float* __restrict__ ldp, float* __restrict__ ld)
{
    const int b = blockIdx.x * 4 + (threadIdx.x >> 6);
    const int lane = threadIdx.x & 63;
    float r = ldp[(long)b * 64 + lane];
#pragma unroll
    for (int off = 32; off; off >>= 1) r += __shfl_xor(r, off, 64);
    if (lane == 0) ld[b] = r;
}

__global__ void cvt_x_bf16(const float* __restrict__ in, u16* __restrict__ out, long n) {
    long i = (long)blockIdx.x * blockDim.x + threadIdx.x;
    long stride = (long)gridDim.x * blockDim.x;
    for (; i < n; i += stride) out[i] = f2bf_r(in[i]);
}

__global__ void transpose_w_bf16(const float* __restrict__ W, u16* __restrict__ WT,
                                 int K, int N) {
    long total = (long)N * K;
    long i = (long)blockIdx.x * blockDim.x + threadIdx.x;
    long stride = (long)gridDim.x * blockDim.x;
    for (; i < total; i += stride) {
        int n = (int)(i / K), k = (int)(i % K);
        WT[i] = f2bf_r(W[(long)k * N + n]);
    }
}

__global__ void transpose_w2_bf16(const float* __restrict__ W, u16* __restrict__ WT, int K) {
    long total = 1536L * K;
    long i = (long)blockIdx.x * blockDim.x + threadIdx.x;
    long stride = (long)gridDim.x * blockDim.x;
    for (; i < total; i += stride) {
        int npad = (int)(i / K), k = (int)(i % K);
        int g = npad / 24, r = npad % 24;
        float v = (r < 23) ? W[(long)k * 1472 + g * 23 + r] : 0.f;
        WT[i] = f2bf_r(v);
    }
}

__global__ void pad_bias2(const float* __restrict__ b2, float* __restrict__ b2p) {
    int c = blockIdx.x * 256 + threadIdx.x;
    if (c < 1536) {
        int g = c / 24, r = c % 24;
        b2p[c] = (r < 23) ? b2[g * 23 + r] : 0.f;
    }
}

__global__ void fill_fail(float* __restrict__ out, long n) {
    long i = (long)blockIdx.x * blockDim.x + threadIdx.x;
    long stride = (long)gridDim.x * blockDim.x;
    for (; i < n; i += stride) out[i] = -1.0f;
}

extern "C" void kernel_launch(void* const* d_in, const int* in_sizes, int n_in,
                              void* d_out, int out_size, void* d_ws, size_t ws_size,
                              hipStream_t stream)
{
    const float* x  = (const float*)d_in[0];
    const float* W0 = (const float*)d_in[1];
    const float* b0 = (const float*)d_in[2];
    const float* W1 = (const float*)d_in[3];
    const float* b1 = (const float*)d_in[4];
    const float* W2 = (const float*)d_in[5];
    const float* b2 = (const float*)d_in[6];
    const int B = in_sizes[0] / 64;   // 65536
    const int D = 64, H = 512, NP = 1536;

    char* ws = (char*)d_ws;
    size_t off = 0;
    u16* W0T = (u16*)(ws + off); off += (size_t)H * D * 2;
    u16* W1T = (u16*)(ws + off); off += (size_t)H * H * 2;
    u16* W2T = (u16*)(ws + off); off += (size_t)NP * H * 2;
    float* b2p = (float*)(ws + off); off += (size_t)NP * 4;
    off = (off + 255) & ~(size_t)255;
    u16*   h1  = (u16*)(ws + off);
    float* ldp = (float*)(ws + off);
    off += (size_t)B * H * 2;
    u16* xb = (u16*)(ws + off);
    u16* h2 = (u16*)(ws + off);
    off += (size_t)B * H * 2;
    size_t need = off;

    float* zout  = (float*)d_out;
    float* ldout = zout + (size_t)B * D;

    if (ws_size < need) {
        fill_fail<<<2048, 256, 0, stream>>>(zout, (long)out_size);
        return;
    }

    cvt_x_bf16<<<2048, 256, 0, stream>>>(x, xb, (long)B * D);
    transpose_w_bf16<<<128, 256, 0, stream>>>(W0, W0T, D, H);
    transpose_w_bf16<<<1024, 256, 0, stream>>>(W1, W1T, H, H);
    transpose_w2_bf16<<<3072, 256, 0, stream>>>(W2, W2T, H);
    pad_bias2<<<6, 256, 0, stream>>>(b2, b2p);

    // 1D grids with internal XCD swizzle (NBX col-blocks per row-block)
    gemm_bt<64, 1, 4><<<2048, 256, 0, stream>>>(xb, W0T, b0, h1, B, H);
    gemm_bt<512, 1, 4><<<2048, 256, 0, stream>>>(h1, W1T, b1, h2, B, H);

    gemm3_rqs<512><<<4096, 256, 0, stream>>>(h2, W2T, b2p, x, zout, ldp);

    ld_reduce<<<B / 4, 256, 0, stream>>>(ldp, ldout);
}